// Round 1
// baseline (60.313 us; speedup 1.0000x reference)
//
#include <hip/hip_runtime.h>

// VQ straight-through forward: quantized = closest + (inputs - closest) == inputs.
// The distance/argmin/gather pipeline only shapes gradients, which are not
// produced here. Forward output is numerically the input tensor (within ~2 ulp
// of the reference's two fp32 roundings), so the optimal kernel is a copy.

__global__ __launch_bounds__(256) void vq_forward_copy(const float4* __restrict__ in,
                                                       float4* __restrict__ out,
                                                       int n4) {
    int i = blockIdx.x * blockDim.x + threadIdx.x;
    if (i < n4) {
        out[i] = in[i];
    }
}

// Tail handler for element counts not divisible by 4 (not expected here:
// 32*32*32*64 = 2,097,152 is divisible by 4, but keep it robust).
__global__ __launch_bounds__(64) void vq_forward_copy_tail(const float* __restrict__ in,
                                                           float* __restrict__ out,
                                                           int start, int n) {
    int i = start + blockIdx.x * blockDim.x + threadIdx.x;
    if (i < n) {
        out[i] = in[i];
    }
}

extern "C" void kernel_launch(void* const* d_in, const int* in_sizes, int n_in,
                              void* d_out, int out_size, void* d_ws, size_t ws_size,
                              hipStream_t stream) {
    const float* inputs = (const float*)d_in[0];  // [32,32,32,64] fp32
    float* out = (float*)d_out;                   // same shape/dtype

    int n = out_size;          // 2,097,152 elements
    int n4 = n / 4;            // float4 count
    int tail_start = n4 * 4;

    const int block = 256;
    int grid = (n4 + block - 1) / block;   // 2048 blocks
    vq_forward_copy<<<grid, block, 0, stream>>>((const float4*)inputs, (float4*)out, n4);

    int tail = n - tail_start;
    if (tail > 0) {
        vq_forward_copy_tail<<<1, 64, 0, stream>>>(inputs, out, tail_start, n);
    }
}